// Round 6
// baseline (187.880 us; speedup 1.0000x reference)
//
#include <hip/hip_runtime.h>
#include <hip/hip_bf16.h>
#include <stdint.h>

// EncoderBlock: B=8, S=1024, D=512, H=12, HS=42 (padded to 64 for GEMM).
// Only batch 0's attention is used (reference quirk: attn[0] + x).

typedef unsigned short u16;
typedef __attribute__((ext_vector_type(8))) short short8;  // 8 bf16 = 4 VGPRs
typedef __attribute__((ext_vector_type(4))) float f32x4;

__device__ __forceinline__ u16 f2bf(float f) {
  union { float f; unsigned u; } x; x.f = f;
  return (u16)((x.u + 0x7FFFu + ((x.u >> 16) & 1u)) >> 16);  // RNE
}
__device__ __forceinline__ float bf2f(u16 u) {
  union { unsigned u; float f; } x; x.u = ((unsigned)u) << 16;
  return x.f;
}

// async global->LDS, 16B per lane; LDS dest is wave-uniform base + lane*16.
__device__ __forceinline__ void gload_lds16(const u16* g, u16* l) {
  __builtin_amdgcn_global_load_lds(
      (__attribute__((address_space(1))) void*)g,
      (__attribute__((address_space(3))) void*)l, 16, 0, 0);
}

__device__ __forceinline__ float wred_sum(float v) {
#pragma unroll
  for (int off = 32; off > 0; off >>= 1) v += __shfl_xor(v, off, 64);
  return v;
}
__device__ __forceinline__ float wred_max(float v) {
#pragma unroll
  for (int off = 32; off > 0; off >>= 1) v = fmaxf(v, __shfl_xor(v, off, 64));
  return v;
}

// tanh-form GELU: 0.5x(1+tanh(u)) == x / (1 + exp(-2u)), u = c0*x + c1*x^3.
// |dev vs exact erf-GELU| <= ~4e-3 pointwise, ~3e-4 after the w2 contraction.
__device__ __forceinline__ float gelu_fast(float t) {
  const float p = __builtin_fmaf(0.0356774081f, t * t, 0.7978845608f);
  return t / (1.0f + __expf(-2.0f * t * p));
}

#define MFMA16x16(a, b, c) __builtin_amdgcn_mfma_f32_16x16x32_bf16(a, b, c, 0, 0, 0)

// ---------------------------------------------------------------------------
// GEMM: C[m][n] = sum_k A[m][k] * Bt[n][k]   (A,Bt bf16 row-major; Bt is B^T)
// 128x128 tile, BK=32, 4 waves (2x2), mfma_f32_16x16x32_bf16, dbuf LDS
// (r3-measured-best structure: linear layout, one __syncthreads per K-tile,
// next-tile global_load_lds issued before the MFMA cluster).
// XCD-aware block swizzle (T1, bijective: every grid here has nwg%8==0):
// blocks with consecutive swizzled ids (sharing A/B panels) land on one XCD.
// Epilogues: 0=bf16, 1=PV-scaled scatter, 2=f32+bias, 3=gelu->bf16,
//            4=f32+bias+resid, 5=f32 partial (split-K), 6=PV f32 partial.
// ---------------------------------------------------------------------------
enum { EP_BF16 = 0, EP_PV = 1, EP_F32B = 2, EP_GELU = 3, EP_OUT = 4,
       EP_PART = 5, EP_PVPART = 6 };

template <int EP>
__launch_bounds__(256, 4)
__global__ void gemm2(const u16* __restrict__ A, int lda, long sAz,
                      const u16* __restrict__ Bt, int ldb, long sBz,
                      void* __restrict__ Cv, int ldc, long sCz,
                      int K, const float* __restrict__ bias,
                      const float* __restrict__ aux) {
  __shared__ u16 lA[2][128 * 32];  // [buf][m][k] linear, 8KB each
  __shared__ u16 lB[2][128 * 32];

  // bijective XCD swizzle: lin -> (lin&7)*(nwg/8) + lin>>3, then decode
  const int gx = gridDim.x, gy = gridDim.y;
  const int lin = blockIdx.x + gx * (blockIdx.y + gy * blockIdx.z);
  const int nwg = gx * gy * gridDim.z;
  const int wg = (lin & 7) * (nwg >> 3) + (lin >> 3);
  const int bx = wg % gx;
  const int tmp = wg / gx;
  const int by = tmp % gy;
  const int z = tmp / gy;

  const u16* Ab;
  const u16* Bb;
  if (EP == EP_PVPART) {  // z = head*4 + kslice, kslice covers 256 of K
    Ab = A + (long)(z >> 2) * sAz + (z & 3) * 256;
    Bb = Bt + (long)(z >> 2) * sBz + (z & 3) * 256;
  } else {
    Ab = A + (long)z * sAz;
    Bb = Bt + (long)z * sBz;
  }
  const int m0 = bx * 128;
  const int n0 = by * 128;
  const int tid = threadIdx.x;
  const int w = tid >> 6;
  const int l = tid & 63;
  const int wr = w >> 1;
  const int wc = w & 1;
  const int NT = K >> 5;

  f32x4 acc[4][4];
#pragma unroll
  for (int i = 0; i < 4; ++i)
#pragma unroll
    for (int j = 0; j < 4; ++j) acc[i][j] = (f32x4){0.f, 0.f, 0.f, 0.f};

  // staging: wave w covers tile rows [w*32, w*32+32); lane -> row l>>2,
  // 16B granule l&3 (linear; r4 measured source-swizzle as a net loss).
  const int srow = w * 32 + (l >> 2);
  const int sk = (l & 3) * 8;
  const u16* ga0 = Ab + (long)(m0 + srow) * lda + sk;
  const u16* ga1 = Ab + (long)(m0 + srow + 16) * lda + sk;
  const u16* gb0 = Bb + (long)(n0 + srow) * ldb + sk;
  const u16* gb1 = Bb + (long)(n0 + srow + 16) * ldb + sk;
  const int dOff = w * 1024;

  // fragment reads: row = l&15, k-granule = l>>4
  const int aoff = (wr * 64 + (l & 15)) * 32 + (l >> 4) * 8;
  const int boff = (wc * 64 + (l & 15)) * 32 + (l >> 4) * 8;

  // prologue: stage tile 0 into buf 0
  gload_lds16(ga0, &lA[0][dOff]);
  gload_lds16(ga1, &lA[0][dOff + 512]);
  gload_lds16(gb0, &lB[0][dOff]);
  gload_lds16(gb1, &lB[0][dOff + 512]);
  __syncthreads();

  int buf = 0;
  for (int t = 0; t < NT; ++t) {
    short8 af[4], bfv[4];
#pragma unroll
    for (int mi = 0; mi < 4; ++mi)
      af[mi] = *(const short8*)&lA[buf][aoff + mi * 16 * 32];
#pragma unroll
    for (int ni = 0; ni < 4; ++ni)
      bfv[ni] = *(const short8*)&lB[buf][boff + ni * 16 * 32];
    if (t + 1 < NT) {
      const int k0 = (t + 1) * 32;
      const int nb = buf ^ 1;
      gload_lds16(ga0 + k0, &lA[nb][dOff]);
      gload_lds16(ga1 + k0, &lA[nb][dOff + 512]);
      gload_lds16(gb0 + k0, &lB[nb][dOff]);
      gload_lds16(gb1 + k0, &lB[nb][dOff + 512]);
    }
#pragma unroll
    for (int mi = 0; mi < 4; ++mi)
#pragma unroll
      for (int ni = 0; ni < 4; ++ni)
        acc[mi][ni] = MFMA16x16(af[mi], bfv[ni], acc[mi][ni]);
    __syncthreads();
    buf ^= 1;
  }

  // C/D mapping: col = lane&15, row = (lane>>4)*4 + reg  [m89-verified]
  const int rbase = m0 + wr * 64 + (l >> 4) * 4;
  const int cbase = n0 + wc * 64 + (l & 15);
#pragma unroll
  for (int mi = 0; mi < 4; ++mi) {
#pragma unroll
    for (int ni = 0; ni < 4; ++ni) {
#pragma unroll
      for (int j = 0; j < 4; ++j) {
        const int row = rbase + mi * 16 + j;
        const int col = cbase + ni * 16;
        const float v = acc[mi][ni][j];
        if (EP == EP_BF16) {
          ((u16*)Cv)[(long)z * sCz + (long)row * ldc + col] = f2bf(v);
        } else if (EP == EP_PV) {
          if (col < 42) {
            const float iv = aux[z * 1024 + row];
            ((u16*)Cv)[(long)row * ldc + z * 42 + col] = f2bf(v * iv);
          }
        } else if (EP == EP_F32B) {
          ((float*)Cv)[(long)row * ldc + col] = v + bias[col];
        } else if (EP == EP_GELU) {
          ((u16*)Cv)[(long)row * ldc + col] = f2bf(gelu_fast(v + bias[col]));
        } else if (EP == EP_OUT) {
          ((float*)Cv)[(long)row * ldc + col] =
              v + bias[col] + aux[(long)row * ldc + col];
        } else {  // EP_PART / EP_PVPART: raw f32 partial at slice z
          ((float*)Cv)[(long)z * sCz + (long)row * ldc + col] = v;
        }
      }
    }
  }
}

// out = p0 + p1 + b2 + fa  (f32x4 elementwise over [8192][512])
__global__ void combine_mlp2_kernel(const float* __restrict__ p,
                                    const float* __restrict__ fa,
                                    const float* __restrict__ b2,
                                    float* __restrict__ out) {
  const long i = (long)blockIdx.x * 256 + threadIdx.x;  // f32x4 index
  const f32x4 a = ((const f32x4*)p)[i];
  const f32x4 b = ((const f32x4*)(p + 8192L * 512))[i];
  const f32x4 f = ((const f32x4*)fa)[i];
  const f32x4 bb = ((const f32x4*)b2)[i & 127];
  ((f32x4*)out)[i] = a + b + f + bb;
}

// PV combine: cat[row][h*42+e] = invl[h*1024+row] * sum_s part[(h*4+s)][row][e]
__global__ void combine_pv_kernel(const float* __restrict__ part,
                                  const float* __restrict__ invl,
                                  u16* __restrict__ cat) {
  const int blk = blockIdx.x;  // h*1024 + row
  const int h = blk >> 10;
  const int row = blk & 1023;
  const int e = threadIdx.x;   // 64 threads, keep e<42
  if (e >= 42) return;
  const long base = (long)(h * 4) * 131072 + row * 128 + e;
  float v = part[base] + part[base + 131072] + part[base + 2 * 131072] +
            part[base + 3 * 131072];
  cat[(long)row * 512 + h * 42 + e] = f2bf(v * invl[h * 1024 + row]);
}

// ---------------------------------------------------------------------------
// LayerNorm / softmax / prep kernels
// ---------------------------------------------------------------------------
__global__ void ln1_kernel(const float* __restrict__ x,
                           const float* __restrict__ gamma,
                           const float* __restrict__ beta,
                           u16* __restrict__ n1) {
  __shared__ float red[16];
  const int s = blockIdx.x;
  const int t = threadIdx.x;
  const float* row = x + (long)s * 512;
  const float v0 = row[t];
  const float v1 = row[t + 256];
  float sum = wred_sum(v0 + v1);
  float sq = wred_sum(v0 * v0 + v1 * v1);
  if ((t & 63) == 0) { red[t >> 6] = sum; red[8 + (t >> 6)] = sq; }
  __syncthreads();
  sum = red[0] + red[1] + red[2] + red[3];
  sq = red[8] + red[9] + red[10] + red[11];
  const float mu = sum * (1.0f / 512.0f);
  const float rstd = rsqrtf(sq * (1.0f / 512.0f) - mu * mu + 1e-5f);
  n1[(long)s * 512 + t] = f2bf((v0 - mu) * rstd * gamma[t] + beta[t]);
  n1[(long)s * 512 + t + 256] =
      f2bf((v1 - mu) * rstd * gamma[t + 256] + beta[t + 256]);
}

__global__ void ln2_kernel(const float* __restrict__ x,
                           const float* __restrict__ aproj,
                           const float* __restrict__ gamma,
                           const float* __restrict__ beta,
                           float* __restrict__ fa, u16* __restrict__ n2) {
  __shared__ float red[16];
  const int r = blockIdx.x;  // b*1024 + s
  const int t = threadIdx.x;
  const int s = r & 1023;
  const float* xr = x + (long)r * 512;
  const float* ar = aproj + (long)s * 512;
  const float v0 = xr[t] + ar[t];
  const float v1 = xr[t + 256] + ar[t + 256];
  fa[(long)r * 512 + t] = v0;
  fa[(long)r * 512 + t + 256] = v1;
  float sum = wred_sum(v0 + v1);
  float sq = wred_sum(v0 * v0 + v1 * v1);
  if ((t & 63) == 0) { red[t >> 6] = sum; red[8 + (t >> 6)] = sq; }
  __syncthreads();
  sum = red[0] + red[1] + red[2] + red[3];
  sq = red[8] + red[9] + red[10] + red[11];
  const float mu = sum * (1.0f / 512.0f);
  const float rstd = rsqrtf(sq * (1.0f / 512.0f) - mu * mu + 1e-5f);
  n2[(long)r * 512 + t] = f2bf((v0 - mu) * rstd * gamma[t] + beta[t]);
  n2[(long)r * 512 + t + 256] =
      f2bf((v1 - mu) * rstd * gamma[t + 256] + beta[t + 256]);
}

// in-place row softmax over bf16 scores [12*1024][1024]; stores 1/sum
__global__ void softmax_kernel(u16* __restrict__ SP, float* __restrict__ invl) {
  __shared__ float red[16];
  const long row = blockIdx.x;
  u16* p = SP + row * 1024;
  const int t = threadIdx.x;
  uint2 u = ((const uint2*)p)[t];
  const float s0 = bf2f((u16)(u.x & 0xffff));
  const float s1 = bf2f((u16)(u.x >> 16));
  const float s2 = bf2f((u16)(u.y & 0xffff));
  const float s3 = bf2f((u16)(u.y >> 16));
  float m = wred_max(fmaxf(fmaxf(s0, s1), fmaxf(s2, s3)));
  if ((t & 63) == 0) red[t >> 6] = m;
  __syncthreads();
  m = fmaxf(fmaxf(red[0], red[1]), fmaxf(red[2], red[3]));
  const float e0 = __expf(s0 - m), e1 = __expf(s1 - m);
  const float e2 = __expf(s2 - m), e3 = __expf(s3 - m);
  float sum = wred_sum(e0 + e1 + e2 + e3);
  if ((t & 63) == 0) red[8 + (t >> 6)] = sum;
  __syncthreads();
  sum = red[8] + red[9] + red[10] + red[11];
  if (t == 0) invl[row] = 1.0f / sum;
  uint2 o;
  o.x = (unsigned)f2bf(e0) | ((unsigned)f2bf(e1) << 16);
  o.y = (unsigned)f2bf(e2) | ((unsigned)f2bf(e3) << 16);
  ((uint2*)p)[t] = o;
}

__global__ void prep_qkv_kernel(const float* __restrict__ wq,
                                const float* __restrict__ wk,
                                u16* __restrict__ BtQKV, float scale) {
  const int i = blockIdx.x * 256 + threadIdx.x;
  const int n = i >> 9, d = i & 511;
  const int pq = n / 768;
  const int h = (n % 768) >> 6;
  const int e = n & 63;
  float v = 0.f;
  if (e < 42) {
    v = (pq ? wk : wq)[((long)h * 512 + d) * 42 + e];
    if (!pq) v *= scale;
  }
  BtQKV[i] = f2bf(v);
}
__global__ void prep_wvT_kernel(const float* __restrict__ wv,
                                u16* __restrict__ wvT) {
  const int i = blockIdx.x * 256 + threadIdx.x;
  const int r = i >> 9, d = i & 511;
  const int h = r >> 7, e = r & 127;
  wvT[i] = f2bf(e < 42 ? wv[((long)h * 512 + d) * 42 + e] : 0.f);
}

// LDS-tiled transpose: out[n][k] = bf16(in[k][n]); zero-fill k >= Kin.
// grid = (N/64, Kpad/64), block 256. Coalesced on both sides.
__global__ void transpose_bf16_kernel(const float* __restrict__ in,
                                      u16* __restrict__ out, int N, int Kin,
                                      int Kpad) {
  __shared__ float tile[64][65];
  const int n0 = blockIdx.x * 64;
  const int k0 = blockIdx.y * 64;
  const int t = threadIdx.x;
  const int tc = t & 63;
  const int tr = t >> 6;  // 0..3
#pragma unroll
  for (int r = 0; r < 16; ++r) {
    const int kr = tr * 16 + r;
    const int kg = k0 + kr;
    tile[kr][tc] = (kg < Kin) ? in[(long)kg * N + n0 + tc] : 0.f;
  }
  __syncthreads();
  const int nr0 = t >> 4;        // 0..15
  const int kc = (t & 15) * 4;   // 16 lanes x 8B = 128B contiguous per row
#pragma unroll
  for (int p = 0; p < 4; ++p) {
    const int nr = nr0 + p * 16;
    ushort4 v;
    v.x = f2bf(tile[kc + 0][nr]);
    v.y = f2bf(tile[kc + 1][nr]);
    v.z = f2bf(tile[kc + 2][nr]);
    v.w = f2bf(tile[kc + 3][nr]);
    *(ushort4*)&out[(long)(n0 + nr) * Kpad + k0 + kc] = v;
  }
}

__global__ void zero_u16_kernel(u16* __restrict__ p) {
  p[blockIdx.x * 256 + threadIdx.x] = 0;
}

// ---------------------------------------------------------------------------
extern "C" void kernel_launch(void* const* d_in, const int* in_sizes, int n_in,
                              void* d_out, int out_size, void* d_ws,
                              size_t ws_size, hipStream_t stream) {
  const float* x = (const float*)d_in[0];
  const float* wk = (const float*)d_in[1];   // wk before wq in dict order
  const float* wq = (const float*)d_in[2];
  const float* wv = (const float*)d_in[3];
  const float* w_proj = (const float*)d_in[4];
  const float* b_proj = (const float*)d_in[5];
  const float* gamma = (const float*)d_in[6];
  const float* beta = (const float*)d_in[7];
  const float* w1 = (const float*)d_in[8];
  const float* b1 = (const float*)d_in[9];
  const float* w2 = (const float*)d_in[10];
  const float* b2 = (const float*)d_in[11];

  char* base = (char*)d_ws;
  size_t off = 0;
  auto alloc = [&](size_t bytes) -> void* {
    void* p = base + off;
    off += (bytes + 255) & ~(size_t)255;
    return p;
  };
  // [n1..aproj) spans ~37 MB, dead by MLP2 -> split-K partials (33.6 MB)
  // alias offset 0.
  u16* n1 = (u16*)alloc(1024L * 512 * 2);        // LN1(x[0]) bf16
  u16* qkvc = (u16*)alloc(1024L * 1536 * 2);     // [s][(q|k) h e64] bf16
  u16* SP = (u16*)alloc(12L * 1024 * 1024 * 2);  // scores -> P, in-place
  u16* wvT = (u16*)alloc(1536L * 512 * 2);       // [h*128+e][d]
  u16* vt = (u16*)alloc(1536L * 1024 * 2);       // v^T [h*128+e][t]
  u16* cat = (u16*)alloc(1024L * 512 * 2);       // concat heads, pad->512
  float* aproj = (float*)alloc(1024L * 512 * 4); // attn @ w_proj + b_proj
  float* fa = (float*)alloc(8192L * 512 * 4);    // first_added, f32
  u16* n2 = (u16*)alloc(8192L * 512 * 2);        // LN2 bf16
  u16* hbuf = (u16*)alloc(8192L * 2048 * 2);     // gelu(mlp1) bf16
  u16* BtQKV = (u16*)alloc(1536L * 512 * 2);
  u16* BtP = (u16*)alloc(512L * 512 * 2);
  u16* Bt1 = (u16*)alloc(2048L * 512 * 2);
  u16* Bt2 = (u16*)alloc(512L * 2048 * 2);
  float* invl = (float*)alloc(12L * 1024 * 4);
  float* pvpart = (float*)alloc(48L * 1024 * 128 * 4);  // 24 MB PV partials
  float* part = (float*)d_ws;  // MLP2 partials, aliases n1..aproj (dead then)
  (void)ws_size; (void)in_sizes; (void)n_in; (void)out_size;

  const float scale = 0.15430334996209191f;  // 42^-0.5 folded into q weights

  prep_qkv_kernel<<<3072, 256, 0, stream>>>(wq, wk, BtQKV, scale);
  prep_wvT_kernel<<<3072, 256, 0, stream>>>(wv, wvT);
  transpose_bf16_kernel<<<dim3(8, 8), 256, 0, stream>>>(w_proj, BtP, 512, 504, 512);
  transpose_bf16_kernel<<<dim3(32, 8), 256, 0, stream>>>(w1, Bt1, 2048, 512, 512);
  transpose_bf16_kernel<<<dim3(8, 32), 256, 0, stream>>>(w2, Bt2, 512, 2048, 2048);
  zero_u16_kernel<<<2048, 256, 0, stream>>>(cat);
  ln1_kernel<<<1024, 256, 0, stream>>>(x, gamma, beta, n1);

  // q,k = n1 @ {wq*scale, wk}: [1024,1536], K=512   (nwg=96, %8==0)
  gemm2<EP_BF16><<<dim3(8, 12, 1), 256, 0, stream>>>(
      n1, 512, 0, BtQKV, 512, 0, qkvc, 1536, 0, 512, nullptr, nullptr);
  // vt = wvT @ n1^T: [1536,1024], K=512             (nwg=96)
  gemm2<EP_BF16><<<dim3(12, 8, 1), 256, 0, stream>>>(
      wvT, 512, 0, n1, 512, 0, vt, 1024, 0, 512, nullptr, nullptr);
  // scores per head: q_h [1024,64] x k_h^T -> [1024,1024] bf16 (nwg=768)
  gemm2<EP_BF16><<<dim3(8, 8, 12), 256, 0, stream>>>(
      qkvc, 1536, 64, qkvc + 768, 1536, 64, SP, 1024, 1024L * 1024, 64,
      nullptr, nullptr);
  softmax_kernel<<<12288, 256, 0, stream>>>(SP, invl);
  // PV split-K=4: z = h*4+s, each K=256 -> f32 partials (nwg=384)
  gemm2<EP_PVPART><<<dim3(8, 1, 48), 256, 0, stream>>>(
      SP, 1024, 1024L * 1024, vt, 1024, 128L * 1024, pvpart, 128,
      1024L * 128, 256, nullptr, nullptr);
  combine_pv_kernel<<<12288, 64, 0, stream>>>(pvpart, invl, cat);
  // attn_proj = concat @ w_proj + b_proj: [1024,512] f32 (nwg=32)
  gemm2<EP_F32B><<<dim3(8, 4, 1), 256, 0, stream>>>(
      cat, 512, 0, BtP, 512, 0, aproj, 512, 0, 512, b_proj, nullptr);
  ln2_kernel<<<8192, 256, 0, stream>>>(x, aproj, gamma, beta, fa, n2);
  // h = gelu(n2 @ w1 + b1): [8192,2048] bf16 (nwg=1024)
  gemm2<EP_GELU><<<dim3(64, 16, 1), 256, 0, stream>>>(
      n2, 512, 0, Bt1, 512, 0, hbuf, 2048, 0, 512, b1, nullptr);
  // MLP2 split-K=2: partials = h @ w2 slices (z strides K by 1024, nwg=512)
  gemm2<EP_PART><<<dim3(64, 4, 2), 256, 0, stream>>>(
      hbuf, 2048, 1024, Bt2, 2048, 1024, part, 512, 8192L * 512, 1024,
      nullptr, nullptr);
  // out = p0 + p1 + b2 + fa
  combine_mlp2_kernel<<<4096, 256, 0, stream>>>(part, fa, b2, (float*)d_out);
}

// Round 7
// 177.050 us; speedup vs baseline: 1.0612x; 1.0612x over previous
//
#include <hip/hip_runtime.h>
#include <hip/hip_bf16.h>
#include <stdint.h>

// EncoderBlock: B=8, S=1024, D=512, H=12, HS=42 (padded to 64 for GEMM).
// Only batch 0's attention is used (reference quirk: attn[0] + x).

typedef unsigned short u16;
typedef __attribute__((ext_vector_type(8))) short short8;  // 8 bf16 = 4 VGPRs
typedef __attribute__((ext_vector_type(4))) float f32x4;

__device__ __forceinline__ u16 f2bf(float f) {
  union { float f; unsigned u; } x; x.f = f;
  return (u16)((x.u + 0x7FFFu + ((x.u >> 16) & 1u)) >> 16);  // RNE
}
__device__ __forceinline__ float bf2f(u16 u) {
  union { unsigned u; float f; } x; x.u = ((unsigned)u) << 16;
  return x.f;
}

// async global->LDS, 16B per lane; LDS dest is wave-uniform base + lane*16.
__device__ __forceinline__ void gload_lds16(const u16* g, u16* l) {
  __builtin_amdgcn_global_load_lds(
      (__attribute__((address_space(1))) void*)g,
      (__attribute__((address_space(3))) void*)l, 16, 0, 0);
}

__device__ __forceinline__ float wred_sum(float v) {
#pragma unroll
  for (int off = 32; off > 0; off >>= 1) v += __shfl_xor(v, off, 64);
  return v;
}
__device__ __forceinline__ float wred_max(float v) {
#pragma unroll
  for (int off = 32; off > 0; off >>= 1) v = fmaxf(v, __shfl_xor(v, off, 64));
  return v;
}

// tanh-form GELU: 0.5x(1+tanh(u)) == x / (1 + exp(-2u)), u = c0*x + c1*x^3.
__device__ __forceinline__ float gelu_fast(float t) {
  const float p = __builtin_fmaf(0.0356774081f, t * t, 0.7978845608f);
  return t / (1.0f + __expf(-2.0f * t * p));
}

#define MFMA16x16(a, b, c) __builtin_amdgcn_mfma_f32_16x16x32_bf16(a, b, c, 0, 0, 0)

// ---------------------------------------------------------------------------
// GEMM: C[m][n] = sum_k A[m][k] * Bt[n][k]   (A,Bt bf16 row-major; Bt is B^T)
// 128x128 tile, BK=32, 4 waves (2x2), mfma_f32_16x16x32_bf16, dbuf LDS
// (r3/r6-measured-best structure). Bijective XCD swizzle (all grids %8==0).
// Epilogues: 0=bf16, 2=f32+bias, 3=gelu->bf16, 6=PV f32 partial,
//            7=atomicAdd into pre-filled f32 output (split-K, no combine).
// ---------------------------------------------------------------------------
enum { EP_BF16 = 0, EP_F32B = 2, EP_GELU = 3, EP_PVPART = 6, EP_ATOM = 7 };

template <int EP>
__launch_bounds__(256, 4)
__global__ void gemm2(const u16* __restrict__ A, int lda, long sAz,
                      const u16* __restrict__ Bt, int ldb, long sBz,
                      void* __restrict__ Cv, int ldc, long sCz,
                      int K, const float* __restrict__ bias,
                      const float* __restrict__ aux) {
  __shared__ u16 lA[2][128 * 32];  // [buf][m][k] linear, 8KB each
  __shared__ u16 lB[2][128 * 32];

  // bijective XCD swizzle: lin -> (lin&7)*(nwg/8) + lin>>3, then decode
  const int gx = gridDim.x, gy = gridDim.y;
  const int lin = blockIdx.x + gx * (blockIdx.y + gy * blockIdx.z);
  const int nwg = gx * gy * gridDim.z;
  const int wg = (lin & 7) * (nwg >> 3) + (lin >> 3);
  const int bx = wg % gx;
  const int tmp = wg / gx;
  const int by = tmp % gy;
  const int z = tmp / gy;

  const u16* Ab;
  const u16* Bb;
  if (EP == EP_PVPART) {  // z = head*4 + kslice, kslice covers 256 of K
    Ab = A + (long)(z >> 2) * sAz + (z & 3) * 256;
    Bb = Bt + (long)(z >> 2) * sBz + (z & 3) * 256;
  } else {
    Ab = A + (long)z * sAz;  // for EP_ATOM sAz is a k-offset (split-K slice)
    Bb = Bt + (long)z * sBz;
  }
  const int m0 = bx * 128;
  const int n0 = by * 128;
  const int tid = threadIdx.x;
  const int w = tid >> 6;
  const int l = tid & 63;
  const int wr = w >> 1;
  const int wc = w & 1;
  const int NT = K >> 5;

  f32x4 acc[4][4];
#pragma unroll
  for (int i = 0; i < 4; ++i)
#pragma unroll
    for (int j = 0; j < 4; ++j) acc[i][j] = (f32x4){0.f, 0.f, 0.f, 0.f};

  // staging: wave w covers tile rows [w*32, w*32+32); lane -> row l>>2,
  // 16B granule l&3 (linear layout).
  const int srow = w * 32 + (l >> 2);
  const int sk = (l & 3) * 8;
  const u16* ga0 = Ab + (long)(m0 + srow) * lda + sk;
  const u16* ga1 = Ab + (long)(m0 + srow + 16) * lda + sk;
  const u16* gb0 = Bb + (long)(n0 + srow) * ldb + sk;
  const u16* gb1 = Bb + (long)(n0 + srow + 16) * ldb + sk;
  const int dOff = w * 1024;

  // fragment reads: row = l&15, k-granule = l>>4
  const int aoff = (wr * 64 + (l & 15)) * 32 + (l >> 4) * 8;
  const int boff = (wc * 64 + (l & 15)) * 32 + (l >> 4) * 8;

  // prologue: stage tile 0 into buf 0
  gload_lds16(ga0, &lA[0][dOff]);
  gload_lds16(ga1, &lA[0][dOff + 512]);
  gload_lds16(gb0, &lB[0][dOff]);
  gload_lds16(gb1, &lB[0][dOff + 512]);
  __syncthreads();

  int buf = 0;
  for (int t = 0; t < NT; ++t) {
    short8 af[4], bfv[4];
#pragma unroll
    for (int mi = 0; mi < 4; ++mi)
      af[mi] = *(const short8*)&lA[buf][aoff + mi * 16 * 32];
#pragma unroll
    for (int ni = 0; ni < 4; ++ni)
      bfv[ni] = *(const short8*)&lB[buf][boff + ni * 16 * 32];
    if (t + 1 < NT) {
      const int k0 = (t + 1) * 32;
      const int nb = buf ^ 1;
      gload_lds16(ga0 + k0, &lA[nb][dOff]);
      gload_lds16(ga1 + k0, &lA[nb][dOff + 512]);
      gload_lds16(gb0 + k0, &lB[nb][dOff]);
      gload_lds16(gb1 + k0, &lB[nb][dOff + 512]);
    }
#pragma unroll
    for (int mi = 0; mi < 4; ++mi)
#pragma unroll
      for (int ni = 0; ni < 4; ++ni)
        acc[mi][ni] = MFMA16x16(af[mi], bfv[ni], acc[mi][ni]);
    __syncthreads();
    buf ^= 1;
  }

  // C/D mapping: col = lane&15, row = (lane>>4)*4 + reg  [m89-verified]
  const int rbase = m0 + wr * 64 + (l >> 4) * 4;
  const int cbase = n0 + wc * 64 + (l & 15);
#pragma unroll
  for (int mi = 0; mi < 4; ++mi) {
#pragma unroll
    for (int ni = 0; ni < 4; ++ni) {
#pragma unroll
      for (int j = 0; j < 4; ++j) {
        const int row = rbase + mi * 16 + j;
        const int col = cbase + ni * 16;
        const float v = acc[mi][ni][j];
        if (EP == EP_BF16) {
          ((u16*)Cv)[(long)z * sCz + (long)row * ldc + col] = f2bf(v);
        } else if (EP == EP_F32B) {
          ((float*)Cv)[(long)row * ldc + col] = v + bias[col];
        } else if (EP == EP_GELU) {
          ((u16*)Cv)[(long)row * ldc + col] = f2bf(gelu_fast(v + bias[col]));
        } else if (EP == EP_PVPART) {  // raw f32 partial at slice z
          ((float*)Cv)[(long)z * sCz + (long)row * ldc + col] = v;
        } else {  // EP_ATOM: accumulate into pre-filled output
          atomicAdd(&((float*)Cv)[(long)row * ldc + col], v);
        }
      }
    }
  }
}

// PV combine: cat[row][h*42+e] = invl[h*1024+row] * sum_s part[(h*4+s)][row][e]
// exact grid: 2016 blocks x 256 = 12*1024*42 threads, all active.
__global__ void combine_pv_kernel(const float* __restrict__ part,
                                  const float* __restrict__ invl,
                                  u16* __restrict__ cat) {
  const int i = blockIdx.x * 256 + threadIdx.x;  // < 516096
  const int e = i % 42;
  const int rowh = i / 42;
  const int row = rowh & 1023;
  const int h = rowh >> 10;
  const long base = (long)(h * 4) * 131072 + row * 128 + e;
  float v = part[base] + part[base + 131072] + part[base + 2 * 131072] +
            part[base + 3 * 131072];
  cat[(long)row * 512 + h * 42 + e] = f2bf(v * invl[h * 1024 + row]);
}

// ---------------------------------------------------------------------------
// fused prep: weight re-layouts + zero(cat) + LN1, one launch.
// block ranges: [0,3072) BtQKV | [3072,6144) wvT | [6144,6208) tp(w_proj)
// | [6208,6464) tp(w1) | [6464,6720) tp(w2) | [6720,8768) zero cat
// | [8768,9792) ln1
// ---------------------------------------------------------------------------
__device__ __forceinline__ void transpose_body(const float* __restrict__ in,
                                               u16* __restrict__ out, int N,
                                               int Kin, int Kpad, int blk,
                                               int gx, int t, float* smem) {
  const int n0 = (blk % gx) * 64;
  const int k0 = (blk / gx) * 64;
  const int tc = t & 63;
  const int tr = t >> 6;  // 0..3
#pragma unroll
  for (int r = 0; r < 16; ++r) {
    const int kr = tr * 16 + r;
    const int kg = k0 + kr;
    smem[kr * 65 + tc] = (kg < Kin) ? in[(long)kg * N + n0 + tc] : 0.f;
  }
  __syncthreads();
  const int nr0 = t >> 4;       // 0..15
  const int kc = (t & 15) * 4;  // 16 lanes x 8B = 128B contiguous per row
#pragma unroll
  for (int p = 0; p < 4; ++p) {
    const int nr = nr0 + p * 16;
    ushort4 v;
    v.x = f2bf(smem[(kc + 0) * 65 + nr]);
    v.y = f2bf(smem[(kc + 1) * 65 + nr]);
    v.z = f2bf(smem[(kc + 2) * 65 + nr]);
    v.w = f2bf(smem[(kc + 3) * 65 + nr]);
    *(ushort4*)&out[(long)(n0 + nr) * Kpad + k0 + kc] = v;
  }
}

__global__ void prep_fused(const float* __restrict__ wq,
                           const float* __restrict__ wk,
                           const float* __restrict__ wv,
                           const float* __restrict__ w_proj,
                           const float* __restrict__ w1,
                           const float* __restrict__ w2,
                           const float* __restrict__ x,
                           const float* __restrict__ gamma,
                           const float* __restrict__ beta,
                           u16* __restrict__ BtQKV, u16* __restrict__ wvT,
                           u16* __restrict__ BtP, u16* __restrict__ Bt1,
                           u16* __restrict__ Bt2, u16* __restrict__ cat,
                           u16* __restrict__ n1, float scale) {
  __shared__ float smem[64 * 65];
  const int blk = blockIdx.x;
  const int t = threadIdx.x;
  if (blk < 3072) {  // BtQKV [1536][512]: n -> (pq, h, e64); q pre-scaled
    const int i = blk * 256 + t;
    const int n = i >> 9, d = i & 511;
    const int pq = n / 768;
    const int h = (n % 768) >> 6;
    const int e = n & 63;
    float v = 0.f;
    if (e < 42) {
      v = (pq ? wk : wq)[((long)h * 512 + d) * 42 + e];
      if (!pq) v *= scale;
    }
    BtQKV[i] = f2bf(v);
  } else if (blk < 6144) {  // wvT [12*128][512]
    const int i = (blk - 3072) * 256 + t;
    const int r = i >> 9, d = i & 511;
    const int h = r >> 7, e = r & 127;
    wvT[i] = f2bf(e < 42 ? wv[((long)h * 512 + d) * 42 + e] : 0.f);
  } else if (blk < 6208) {  // BtP = w_proj^T (pad 504->512)
    transpose_body(w_proj, BtP, 512, 504, 512, blk - 6144, 8, t, smem);
  } else if (blk < 6464) {  // Bt1 = w1^T
    transpose_body(w1, Bt1, 2048, 512, 512, blk - 6208, 32, t, smem);
  } else if (blk < 6720) {  // Bt2 = w2^T
    transpose_body(w2, Bt2, 512, 2048, 2048, blk - 6464, 8, t, smem);
  } else if (blk < 8768) {  // zero cat
    cat[(blk - 6720) * 256 + t] = 0;
  } else {  // ln1 over x[0]: one block per row s
    const int s = blk - 8768;
    const float* row = x + (long)s * 512;
    const float v0 = row[t];
    const float v1 = row[t + 256];
    float sum = wred_sum(v0 + v1);
    float sq = wred_sum(v0 * v0 + v1 * v1);
    if ((t & 63) == 0) { smem[t >> 6] = sum; smem[8 + (t >> 6)] = sq; }
    __syncthreads();
    sum = smem[0] + smem[1] + smem[2] + smem[3];
    sq = smem[8] + smem[9] + smem[10] + smem[11];
    const float mu = sum * (1.0f / 512.0f);
    const float rstd = rsqrtf(sq * (1.0f / 512.0f) - mu * mu + 1e-5f);
    n1[(long)s * 512 + t] = f2bf((v0 - mu) * rstd * gamma[t] + beta[t]);
    n1[(long)s * 512 + t + 256] =
        f2bf((v1 - mu) * rstd * gamma[t + 256] + beta[t + 256]);
  }
}

// ln2: fa = x + aproj (bcast over batch); n2 = LN(fa); outp = fa + b2
// (pre-fills the final output so MLP2 can atomicAdd into it).
__global__ void ln2_kernel(const float* __restrict__ x,
                           const float* __restrict__ aproj,
                           const float* __restrict__ gamma,
                           const float* __restrict__ beta,
                           const float* __restrict__ b2,
                           float* __restrict__ fa, u16* __restrict__ n2,
                           float* __restrict__ outp) {
  __shared__ float red[16];
  const int r = blockIdx.x;  // b*1024 + s
  const int t = threadIdx.x;
  const int s = r & 1023;
  const float* xr = x + (long)r * 512;
  const float* ar = aproj + (long)s * 512;
  const float v0 = xr[t] + ar[t];
  const float v1 = xr[t + 256] + ar[t + 256];
  fa[(long)r * 512 + t] = v0;
  fa[(long)r * 512 + t + 256] = v1;
  outp[(long)r * 512 + t] = v0 + b2[t];
  outp[(long)r * 512 + t + 256] = v1 + b2[t + 256];
  float sum = wred_sum(v0 + v1);
  float sq = wred_sum(v0 * v0 + v1 * v1);
  if ((t & 63) == 0) { red[t >> 6] = sum; red[8 + (t >> 6)] = sq; }
  __syncthreads();
  sum = red[0] + red[1] + red[2] + red[3];
  sq = red[8] + red[9] + red[10] + red[11];
  const float mu = sum * (1.0f / 512.0f);
  const float rstd = rsqrtf(sq * (1.0f / 512.0f) - mu * mu + 1e-5f);
  n2[(long)r * 512 + t] = f2bf((v0 - mu) * rstd * gamma[t] + beta[t]);
  n2[(long)r * 512 + t + 256] =
      f2bf((v1 - mu) * rstd * gamma[t + 256] + beta[t + 256]);
}

// in-place row softmax over bf16 scores [12*1024][1024]; stores 1/sum
__global__ void softmax_kernel(u16* __restrict__ SP, float* __restrict__ invl) {
  __shared__ float red[16];
  const long row = blockIdx.x;
  u16* p = SP + row * 1024;
  const int t = threadIdx.x;
  uint2 u = ((const uint2*)p)[t];
  const float s0 = bf2f((u16)(u.x & 0xffff));
  const float s1 = bf2f((u16)(u.x >> 16));
  const float s2 = bf2f((u16)(u.y & 0xffff));
  const float s3 = bf2f((u16)(u.y >> 16));
  float m = wred_max(fmaxf(fmaxf(s0, s1), fmaxf(s2, s3)));
  if ((t & 63) == 0) red[t >> 6] = m;
  __syncthreads();
  m = fmaxf(fmaxf(red[0], red[1]), fmaxf(red[2], red[3]));
  const float e0 = __expf(s0 - m), e1 = __expf(s1 - m);
  const float e2 = __expf(s2 - m), e3 = __expf(s3 - m);
  float sum = wred_sum(e0 + e1 + e2 + e3);
  if ((t & 63) == 0) red[8 + (t >> 6)] = sum;
  __syncthreads();
  sum = red[8] + red[9] + red[10] + red[11];
  if (t == 0) invl[row] = 1.0f / sum;
  uint2 o;
  o.x = (unsigned)f2bf(e0) | ((unsigned)f2bf(e1) << 16);
  o.y = (unsigned)f2bf(e2) | ((unsigned)f2bf(e3) << 16);
  ((uint2*)p)[t] = o;
}

// ---------------------------------------------------------------------------
extern "C" void kernel_launch(void* const* d_in, const int* in_sizes, int n_in,
                              void* d_out, int out_size, void* d_ws,
                              size_t ws_size, hipStream_t stream) {
  const float* x = (const float*)d_in[0];
  const float* wk = (const float*)d_in[1];   // wk before wq in dict order
  const float* wq = (const float*)d_in[2];
  const float* wv = (const float*)d_in[3];
  const float* w_proj = (const float*)d_in[4];
  const float* b_proj = (const float*)d_in[5];
  const float* gamma = (const float*)d_in[6];
  const float* beta = (const float*)d_in[7];
  const float* w1 = (const float*)d_in[8];
  const float* b1 = (const float*)d_in[9];
  const float* w2 = (const float*)d_in[10];
  const float* b2 = (const float*)d_in[11];

  char* base = (char*)d_ws;
  size_t off = 0;
  auto alloc = [&](size_t bytes) -> void* {
    void* p = base + off;
    off += (bytes + 255) & ~(size_t)255;
    return p;
  };
  u16* n1 = (u16*)alloc(1024L * 512 * 2);        // LN1(x[0]) bf16
  u16* qkvc = (u16*)alloc(1024L * 1536 * 2);     // [s][(q|k) h e64] bf16
  u16* SP = (u16*)alloc(12L * 1024 * 1024 * 2);  // scores -> P, in-place
  u16* wvT = (u16*)alloc(1536L * 512 * 2);       // [h*128+e][d]
  u16* vt = (u16*)alloc(1536L * 1024 * 2);       // v^T [h*128+e][t]
  u16* cat = (u16*)alloc(1024L * 512 * 2);       // concat heads, pad->512
  float* aproj = (float*)alloc(1024L * 512 * 4); // attn @ w_proj + b_proj
  float* fa = (float*)alloc(8192L * 512 * 4);    // first_added, f32
  u16* n2 = (u16*)alloc(8192L * 512 * 2);        // LN2 bf16
  u16* hbuf = (u16*)alloc(8192L * 2048 * 2);     // gelu(mlp1) bf16
  u16* BtQKV = (u16*)alloc(1536L * 512 * 2);
  u16* BtP = (u16*)alloc(512L * 512 * 2);
  u16* Bt1 = (u16*)alloc(2048L * 512 * 2);
  u16* Bt2 = (u16*)alloc(512L * 2048 * 2);
  float* invl = (float*)alloc(12L * 1024 * 4);
  float* pvpart = (float*)alloc(48L * 1024 * 128 * 4);  // 24 MB PV partials
  (void)ws_size; (void)in_sizes; (void)n_in; (void)out_size;

  const float scale = 0.15430334996209191f;  // 42^-0.5 folded into q weights

  // all prep + LN1 in one launch (9792 blocks)
  prep_fused<<<9792, 256, 0, stream>>>(wq, wk, wv, w_proj, w1, w2, x, gamma,
                                       beta, BtQKV, wvT, BtP, Bt1, Bt2, cat,
                                       n1, scale);

  // q,k = n1 @ {wq*scale, wk}: [1024,1536], K=512   (nwg=96)
  gemm2<EP_BF16><<<dim3(8, 12, 1), 256, 0, stream>>>(
      n1, 512, 0, BtQKV, 512, 0, qkvc, 1536, 0, 512, nullptr, nullptr);
  // vt = wvT @ n1^T: [1536,1024], K=512             (nwg=96)
  gemm2<EP_BF16><<<dim3(12, 8, 1), 256, 0, stream>>>(
      wvT, 512, 0, n1, 512, 0, vt, 1024, 0, 512, nullptr, nullptr);
  // scores per head: q_h [1024,64] x k_h^T -> [1024,1024] bf16 (nwg=768)
  gemm2<EP_BF16><<<dim3(8, 8, 12), 256, 0, stream>>>(
      qkvc, 1536, 64, qkvc + 768, 1536, 64, SP, 1024, 1024L * 1024, 64,
      nullptr, nullptr);
  softmax_kernel<<<12288, 256, 0, stream>>>(SP, invl);
  // PV split-K=4: z = h*4+s, each K=256 -> f32 partials (nwg=384)
  gemm2<EP_PVPART><<<dim3(8, 1, 48), 256, 0, stream>>>(
      SP, 1024, 1024L * 1024, vt, 1024, 128L * 1024, pvpart, 128,
      1024L * 128, 256, nullptr, nullptr);
  combine_pv_kernel<<<2016, 256, 0, stream>>>(pvpart, invl, cat);
  // attn_proj = concat @ w_proj + b_proj: [1024,512] f32 (nwg=32)
  gemm2<EP_F32B><<<dim3(8, 4, 1), 256, 0, stream>>>(
      cat, 512, 0, BtP, 512, 0, aproj, 512, 0, 512, b_proj, nullptr);
  // ln2 also pre-fills d_out = fa + b2 for the atomic MLP2 epilogue
  ln2_kernel<<<8192, 256, 0, stream>>>(x, aproj, gamma, beta, b2, fa, n2,
                                       (float*)d_out);
  // h = gelu(n2 @ w1 + b1): [8192,2048] bf16 (nwg=1024)
  gemm2<EP_GELU><<<dim3(64, 16, 1), 256, 0, stream>>>(
      n2, 512, 0, Bt1, 512, 0, hbuf, 2048, 0, 512, b1, nullptr);
  // MLP2 split-K=2 (z-slices offset K by 1024): atomicAdd into d_out (nwg=512)
  gemm2<EP_ATOM><<<dim3(64, 4, 2), 256, 0, stream>>>(
      hbuf, 2048, 1024, Bt2, 2048, 1024, d_out, 512, 0, 1024, nullptr,
      nullptr);
}

// Round 8
// 165.162 us; speedup vs baseline: 1.1375x; 1.0720x over previous
//
#include <hip/hip_runtime.h>
#include <hip/hip_bf16.h>
#include <stdint.h>

// EncoderBlock: B=8, S=1024, D=512, H=12, HS=42 (padded to 64 for GEMM).
// Only batch 0's attention is used (reference quirk: attn[0] + x).

typedef unsigned short u16;
typedef __attribute__((ext_vector_type(8))) short short8;  // 8 bf16 = 4 VGPRs
typedef __attribute__((ext_vector_type(4))) float f32x4;

__device__ __forceinline__ u16 f2bf(float f) {
  union { float f; unsigned u; } x; x.f = f;
  return (u16)((x.u + 0x7FFFu + ((x.u >> 16) & 1u)) >> 16);  // RNE
}
__device__ __forceinline__ float bf2f(u16 u) {
  union { unsigned u; float f; } x; x.u = ((unsigned)u) << 16;
  return x.f;
}

// async global->LDS, 16B per lane; LDS dest is wave-uniform base + lane*16.
__device__ __forceinline__ void gload_lds16(const u16* g, u16* l) {
  __builtin_amdgcn_global_load_lds(
      (__attribute__((address_space(1))) void*)g,
      (__attribute__((address_space(3))) void*)l, 16, 0, 0);
}

__device__ __forceinline__ float wred_sum(float v) {
#pragma unroll
  for (int off = 32; off > 0; off >>= 1) v += __shfl_xor(v, off, 64);
  return v;
}

// tanh-form GELU: 0.5x(1+tanh(u)) == x / (1 + exp(-2u)), u = c0*x + c1*x^3.
__device__ __forceinline__ float gelu_fast(float t) {
  const float p = __builtin_fmaf(0.0356774081f, t * t, 0.7978845608f);
  return t / (1.0f + __expf(-2.0f * t * p));
}

#define MFMA16x16(a, b, c) __builtin_amdgcn_mfma_f32_16x16x32_bf16(a, b, c, 0, 0, 0)

// ---------------------------------------------------------------------------
// GEMM: C[m][n] = sum_k A[m][k] * Bt[n][k]   (A,Bt bf16 row-major; Bt is B^T)
// 128x128 tile, BK=32, 4 waves (2x2), dbuf LDS, one barrier per K-tile
// (r3/r6-measured-best). Bijective XCD swizzle (all grids %8==0).
// ---------------------------------------------------------------------------
enum { EP_BF16 = 0, EP_F32B = 2, EP_GELU = 3, EP_ATOM = 7 };

template <int EP>
__launch_bounds__(256, 4)
__global__ void gemm2(const u16* __restrict__ A, int lda, long sAz,
                      const u16* __restrict__ Bt, int ldb, long sBz,
                      void* __restrict__ Cv, int ldc, long sCz,
                      int K, const float* __restrict__ bias) {
  __shared__ u16 lA[2][128 * 32];  // [buf][m][k] linear, 8KB each
  __shared__ u16 lB[2][128 * 32];

  // bijective XCD swizzle: lin -> (lin&7)*(nwg/8) + lin>>3, then decode
  const int gx = gridDim.x, gy = gridDim.y;
  const int lin = blockIdx.x + gx * (blockIdx.y + gy * blockIdx.z);
  const int nwg = gx * gy * gridDim.z;
  const int wg = (lin & 7) * (nwg >> 3) + (lin >> 3);
  const int bx = wg % gx;
  const int tmp = wg / gx;
  const int by = tmp % gy;
  const int z = tmp / gy;

  const u16* Ab = A + (long)z * sAz;  // for EP_ATOM sAz is a k-offset
  const u16* Bb = Bt + (long)z * sBz;
  const int m0 = bx * 128;
  const int n0 = by * 128;
  const int tid = threadIdx.x;
  const int w = tid >> 6;
  const int l = tid & 63;
  const int wr = w >> 1;
  const int wc = w & 1;
  const int NT = K >> 5;

  f32x4 acc[4][4];
#pragma unroll
  for (int i = 0; i < 4; ++i)
#pragma unroll
    for (int j = 0; j < 4; ++j) acc[i][j] = (f32x4){0.f, 0.f, 0.f, 0.f};

  const int srow = w * 32 + (l >> 2);
  const int sk = (l & 3) * 8;
  const u16* ga0 = Ab + (long)(m0 + srow) * lda + sk;
  const u16* ga1 = Ab + (long)(m0 + srow + 16) * lda + sk;
  const u16* gb0 = Bb + (long)(n0 + srow) * ldb + sk;
  const u16* gb1 = Bb + (long)(n0 + srow + 16) * ldb + sk;
  const int dOff = w * 1024;

  const int aoff = (wr * 64 + (l & 15)) * 32 + (l >> 4) * 8;
  const int boff = (wc * 64 + (l & 15)) * 32 + (l >> 4) * 8;

  gload_lds16(ga0, &lA[0][dOff]);
  gload_lds16(ga1, &lA[0][dOff + 512]);
  gload_lds16(gb0, &lB[0][dOff]);
  gload_lds16(gb1, &lB[0][dOff + 512]);
  __syncthreads();

  int buf = 0;
  for (int t = 0; t < NT; ++t) {
    short8 af[4], bfv[4];
#pragma unroll
    for (int mi = 0; mi < 4; ++mi)
      af[mi] = *(const short8*)&lA[buf][aoff + mi * 16 * 32];
#pragma unroll
    for (int ni = 0; ni < 4; ++ni)
      bfv[ni] = *(const short8*)&lB[buf][boff + ni * 16 * 32];
    if (t + 1 < NT) {
      const int k0 = (t + 1) * 32;
      const int nb = buf ^ 1;
      gload_lds16(ga0 + k0, &lA[nb][dOff]);
      gload_lds16(ga1 + k0, &lA[nb][dOff + 512]);
      gload_lds16(gb0 + k0, &lB[nb][dOff]);
      gload_lds16(gb1 + k0, &lB[nb][dOff + 512]);
    }
#pragma unroll
    for (int mi = 0; mi < 4; ++mi)
#pragma unroll
      for (int ni = 0; ni < 4; ++ni)
        acc[mi][ni] = MFMA16x16(af[mi], bfv[ni], acc[mi][ni]);
    __syncthreads();
    buf ^= 1;
  }

  // C/D mapping: col = lane&15, row = (lane>>4)*4 + reg  [m89-verified]
  const int rbase = m0 + wr * 64 + (l >> 4) * 4;
  const int cbase = n0 + wc * 64 + (l & 15);
#pragma unroll
  for (int mi = 0; mi < 4; ++mi) {
#pragma unroll
    for (int ni = 0; ni < 4; ++ni) {
#pragma unroll
      for (int j = 0; j < 4; ++j) {
        const int row = rbase + mi * 16 + j;
        const int col = cbase + ni * 16;
        const float v = acc[mi][ni][j];
        if (EP == EP_BF16) {
          ((u16*)Cv)[(long)z * sCz + (long)row * ldc + col] = f2bf(v);
        } else if (EP == EP_F32B) {
          ((float*)Cv)[(long)row * ldc + col] = v + bias[col];
        } else if (EP == EP_GELU) {
          ((u16*)Cv)[(long)row * ldc + col] = f2bf(gelu_fast(v + bias[col]));
        } else {  // EP_ATOM: accumulate into pre-filled output
          atomicAdd(&((float*)Cv)[(long)row * ldc + col], v);
        }
      }
    }
  }
}

// ---------------------------------------------------------------------------
// flash attention: one block per (head, 64-row q-tile); 256 thr, 4 waves,
// each wave owns 16 q-rows. Per kv-tile(64): S=Q@K^T (16 MFMA, gemm2-style
// A/Bt operands), online softmax in C/D regs (16-lane-group shfl reduces),
// P -> per-wave-private LDS (XOR-swizzled) -> A-frags, O += P@V (vt as Bt).
// K/V double-buffered, one barrier per tile. All LDS tiles [R][64] use
// granule swizzle phys = g ^ (row&7), applied on BOTH stage-source and read.
// ---------------------------------------------------------------------------
__device__ __forceinline__ short8 frag_read(const u16* base, int row, int ks,
                                            int l) {
  const int g = (ks * 4 + (l >> 4)) ^ (l & 7);
  return *(const short8*)&base[row * 64 + g * 8];
}

__launch_bounds__(256, 2)
__global__ void flash_attn(const u16* __restrict__ qkvc,
                           const u16* __restrict__ vt,
                           u16* __restrict__ cat) {
  __shared__ u16 lQ[64 * 64];      // 8KB
  __shared__ u16 lK[2][64 * 64];   // 16KB
  __shared__ u16 lV[2][64 * 64];   // 16KB (rows = e, cols = kv; from vt)
  __shared__ u16 lP[4][16 * 64];   // 8KB, per-wave private
  const int h = blockIdx.x;
  const int q0 = blockIdx.y * 64;
  const int tid = threadIdx.x;
  const int w = tid >> 6;
  const int l = tid & 63;
  const int sg = ((l & 7) ^ (l >> 3)) * 8;  // inverse-swizzled source granule
  const int sr = w * 8 + (l >> 3);          // stage row within 32-row chunk

#define FA_STAGE(t_, b_)                                                    \
  do {                                                                      \
    const int kv_ = (t_) * 64;                                              \
    gload_lds16(qkvc + (long)(kv_ + sr) * 1536 + 768 + h * 64 + sg,         \
                lK[b_] + w * 8 * 64);                                       \
    gload_lds16(qkvc + (long)(kv_ + 32 + sr) * 1536 + 768 + h * 64 + sg,    \
                lK[b_] + (32 + w * 8) * 64);                                \
    gload_lds16(vt + (long)(h * 128 + sr) * 1024 + kv_ + sg,                \
                lV[b_] + w * 8 * 64);                                       \
    gload_lds16(vt + (long)(h * 128 + 32 + sr) * 1024 + kv_ + sg,           \
                lV[b_] + (32 + w * 8) * 64);                                \
  } while (0)

  // prologue: Q (64x64) + K/V tile 0
  gload_lds16(qkvc + (long)(q0 + sr) * 1536 + h * 64 + sg, lQ + w * 8 * 64);
  gload_lds16(qkvc + (long)(q0 + 32 + sr) * 1536 + h * 64 + sg,
              lQ + (32 + w * 8) * 64);
  FA_STAGE(0, 0);
  __syncthreads();

  const short8 qf0 = frag_read(lQ, w * 16 + (l & 15), 0, l);
  const short8 qf1 = frag_read(lQ, w * 16 + (l & 15), 1, l);

  f32x4 accO[4];
  float m_run[4], l_run[4];
#pragma unroll
  for (int i = 0; i < 4; ++i) {
    accO[i] = (f32x4){0.f, 0.f, 0.f, 0.f};
    m_run[i] = -3.0e38f;
    l_run[i] = 0.f;
  }

  int buf = 0;
  for (int t = 0; t < 16; ++t) {
    if (t + 1 < 16) FA_STAGE(t + 1, buf ^ 1);
    // S = Q @ K^T : s[ni] covers cols ni*16..+16, rows = this wave's 16 q
    f32x4 s[4];
#pragma unroll
    for (int ni = 0; ni < 4; ++ni) {
      const short8 kf0 = frag_read(lK[buf], ni * 16 + (l & 15), 0, l);
      const short8 kf1 = frag_read(lK[buf], ni * 16 + (l & 15), 1, l);
      s[ni] = MFMA16x16(qf0, kf0, ((f32x4){0.f, 0.f, 0.f, 0.f}));
      s[ni] = MFMA16x16(qf1, kf1, s[ni]);
    }
    // online softmax; lane's rows: (l>>4)*4 + j (replicated over 16 lanes)
#pragma unroll
    for (int j = 0; j < 4; ++j) {
      float mx = fmaxf(fmaxf(s[0][j], s[1][j]), fmaxf(s[2][j], s[3][j]));
      mx = fmaxf(mx, __shfl_xor(mx, 1));
      mx = fmaxf(mx, __shfl_xor(mx, 2));
      mx = fmaxf(mx, __shfl_xor(mx, 4));
      mx = fmaxf(mx, __shfl_xor(mx, 8));
      const float mn = fmaxf(m_run[j], mx);
      const float corr = __expf(m_run[j] - mn);
      m_run[j] = mn;
      float ps = 0.f;
#pragma unroll
      for (int ni = 0; ni < 4; ++ni) {
        const float p = __expf(s[ni][j] - mn);
        s[ni][j] = p;
        ps += p;
      }
      ps += __shfl_xor(ps, 1);
      ps += __shfl_xor(ps, 2);
      ps += __shfl_xor(ps, 4);
      ps += __shfl_xor(ps, 8);
      l_run[j] = l_run[j] * corr + ps;
#pragma unroll
      for (int ne = 0; ne < 4; ++ne) accO[ne][j] *= corr;
    }
    // P -> LDS (bf16, swizzled); region private to this wave
#pragma unroll
    for (int ni = 0; ni < 4; ++ni) {
#pragma unroll
      for (int j = 0; j < 4; ++j) {
        const int row = (l >> 4) * 4 + j;
        const int col = ni * 16 + (l & 15);
        const int boff = row * 128 + (((col >> 3) ^ (row & 7)) << 4) +
                         (col & 7) * 2;
        *(u16*)((char*)lP[w] + boff) = f2bf(s[ni][j]);
      }
    }
    asm volatile("s_waitcnt lgkmcnt(0)" ::: "memory");
    __builtin_amdgcn_sched_barrier(0);
    // O += P @ V  (vt rows = e, as Bt)
    const short8 pf0 = frag_read(lP[w], (l & 15), 0, l);
    const short8 pf1 = frag_read(lP[w], (l & 15), 1, l);
#pragma unroll
    for (int ne = 0; ne < 4; ++ne) {
      const short8 vf0 = frag_read(lV[buf], ne * 16 + (l & 15), 0, l);
      const short8 vf1 = frag_read(lV[buf], ne * 16 + (l & 15), 1, l);
      accO[ne] = MFMA16x16(pf0, vf0, accO[ne]);
      accO[ne] = MFMA16x16(pf1, vf1, accO[ne]);
    }
    __syncthreads();
    buf ^= 1;
  }
#undef FA_STAGE

  // epilogue: O/l, keep e<42, scatter into concat
#pragma unroll
  for (int j = 0; j < 4; ++j) {
    const float inv = 1.0f / l_run[j];
    const int row = q0 + w * 16 + (l >> 4) * 4 + j;
#pragma unroll
    for (int ne = 0; ne < 4; ++ne) {
      const int e = ne * 16 + (l & 15);
      if (e < 42)
        cat[(long)row * 512 + h * 42 + e] = f2bf(accO[ne][j] * inv);
    }
  }
}

// ---------------------------------------------------------------------------
// fused prep: weight re-layouts + zero(cat) + LN1, one launch.
// ---------------------------------------------------------------------------
__device__ __forceinline__ void transpose_body(const float* __restrict__ in,
                                               u16* __restrict__ out, int N,
                                               int Kin, int Kpad, int blk,
                                               int gx, int t, float* smem) {
  const int n0 = (blk % gx) * 64;
  const int k0 = (blk / gx) * 64;
  const int tc = t & 63;
  const int tr = t >> 6;  // 0..3
#pragma unroll
  for (int r = 0; r < 16; ++r) {
    const int kr = tr * 16 + r;
    const int kg = k0 + kr;
    smem[kr * 65 + tc] = (kg < Kin) ? in[(long)kg * N + n0 + tc] : 0.f;
  }
  __syncthreads();
  const int nr0 = t >> 4;       // 0..15
  const int kc = (t & 15) * 4;  // 16 lanes x 8B = 128B contiguous per row
#pragma unroll
  for (int p = 0; p < 4; ++p) {
    const int nr = nr0 + p * 16;
    ushort4 v;
    v.x = f2bf(smem[(kc + 0) * 65 + nr]);
    v.y = f2bf(smem[(kc + 1) * 65 + nr]);
    v.z = f2bf(smem[(kc + 2) * 65 + nr]);
    v.w = f2bf(smem[(kc + 3) * 65 + nr]);
    *(ushort4*)&out[(long)(n0 + nr) * Kpad + k0 + kc] = v;
  }
}

__device__ __forceinline__ float wredsum_lane(float v) {
#pragma unroll
  for (int off = 32; off > 0; off >>= 1) v += __shfl_xor(v, off, 64);
  return v;
}

__global__ void prep_fused(const float* __restrict__ wq,
                           const float* __restrict__ wk,
                           const float* __restrict__ wv,
                           const float* __restrict__ w_proj,
                           const float* __restrict__ w1,
                           const float* __restrict__ w2,
                           const float* __restrict__ x,
                           const float* __restrict__ gamma,
                           const float* __restrict__ beta,
                           u16* __restrict__ BtQKV, u16* __restrict__ wvT,
                           u16* __restrict__ BtP, u16* __restrict__ Bt1,
                           u16* __restrict__ Bt2, u16* __restrict__ cat,
                           u16* __restrict__ n1, float scale) {
  __shared__ float smem[64 * 65];
  const int blk = blockIdx.x;
  const int t = threadIdx.x;
  if (blk < 3072) {  // BtQKV [1536][512]: n -> (pq, h, e64); q pre-scaled
    const int i = blk * 256 + t;
    const int n = i >> 9, d = i & 511;
    const int pq = n / 768;
    const int h = (n % 768) >> 6;
    const int e = n & 63;
    float v = 0.f;
    if (e < 42) {
      v = (pq ? wk : wq)[((long)h * 512 + d) * 42 + e];
      if (!pq) v *= scale;
    }
    BtQKV[i] = f2bf(v);
  } else if (blk < 6144) {  // wvT [12*128][512]
    const int i = (blk - 3072) * 256 + t;
    const int r = i >> 9, d = i & 511;
    const int h = r >> 7, e = r & 127;
    wvT[i] = f2bf(e < 42 ? wv[((long)h * 512 + d) * 42 + e] : 0.f);
  } else if (blk < 6208) {  // BtP = w_proj^T (pad 504->512)
    transpose_body(w_proj, BtP, 512, 504, 512, blk - 6144, 8, t, smem);
  } else if (blk < 6464) {  // Bt1 = w1^T
    transpose_body(w1, Bt1, 2048, 512, 512, blk - 6208, 32, t, smem);
  } else if (blk < 6720) {  // Bt2 = w2^T
    transpose_body(w2, Bt2, 512, 2048, 2048, blk - 6464, 8, t, smem);
  } else if (blk < 8768) {  // zero cat
    cat[(blk - 6720) * 256 + t] = 0;
  } else {  // ln1 over x[0]
    const int s = blk - 8768;
    const float* row = x + (long)s * 512;
    const float v0 = row[t];
    const float v1 = row[t + 256];
    float sum = wredsum_lane(v0 + v1);
    float sq = wredsum_lane(v0 * v0 + v1 * v1);
    if ((t & 63) == 0) { smem[t >> 6] = sum; smem[8 + (t >> 6)] = sq; }
    __syncthreads();
    sum = smem[0] + smem[1] + smem[2] + smem[3];
    sq = smem[8] + smem[9] + smem[10] + smem[11];
    const float mu = sum * (1.0f / 512.0f);
    const float rstd = rsqrtf(sq * (1.0f / 512.0f) - mu * mu + 1e-5f);
    n1[(long)s * 512 + t] = f2bf((v0 - mu) * rstd * gamma[t] + beta[t]);
    n1[(long)s * 512 + t + 256] =
        f2bf((v1 - mu) * rstd * gamma[t + 256] + beta[t + 256]);
  }
}

// ln2: v = x + aproj (bcast); n2 = LN(v); outp = v + b2 (pre-fill for MLP2's
// atomic epilogue). No separate fa buffer.
__global__ void ln2_kernel(const float* __restrict__ x,
                           const float* __restrict__ aproj,
                           const float* __restrict__ gamma,
                           const float* __restrict__ beta,
                           const float* __restrict__ b2,
                           u16* __restrict__ n2, float* __restrict__ outp) {
  __shared__ float red[16];
  const int r = blockIdx.x;  // b*1024 + s
  const int t = threadIdx.x;
  const int s = r & 1023;
  const float* xr = x + (long)r * 512;
  const float* ar = aproj + (long)s * 512;
  const float v0 = xr[t] + ar[t];
  const float v1 = xr[t + 256] + ar[t + 256];
  outp[(long)r * 512 + t] = v0 + b2[t];
  outp[(long)r * 512 + t + 256] = v1 + b2[t + 256];
  float sum = wred_sum(v0 + v1);
  float sq = wred_sum(v0 * v0 + v1 * v1);
  if ((t & 63) == 0) { red[t >> 6] = sum; red[8 + (t >> 6)] = sq; }
  __syncthreads();
  sum = red[0] + red[1] + red[2] + red[3];
  sq = red[8] + red[9] + red[10] + red[11];
  const float mu = sum * (1.0f / 512.0f);
  const float rstd = rsqrtf(sq * (1.0f / 512.0f) - mu * mu + 1e-5f);
  n2[(long)r * 512 + t] = f2bf((v0 - mu) * rstd * gamma[t] + beta[t]);
  n2[(long)r * 512 + t + 256] =
      f2bf((v1 - mu) * rstd * gamma[t + 256] + beta[t + 256]);
}

// ---------------------------------------------------------------------------
extern "C" void kernel_launch(void* const* d_in, const int* in_sizes, int n_in,
                              void* d_out, int out_size, void* d_ws,
                              size_t ws_size, hipStream_t stream) {
  const float* x = (const float*)d_in[0];
  const float* wk = (const float*)d_in[1];   // wk before wq in dict order
  const float* wq = (const float*)d_in[2];
  const float* wv = (const float*)d_in[3];
  const float* w_proj = (const float*)d_in[4];
  const float* b_proj = (const float*)d_in[5];
  const float* gamma = (const float*)d_in[6];
  const float* beta = (const float*)d_in[7];
  const float* w1 = (const float*)d_in[8];
  const float* b1 = (const float*)d_in[9];
  const float* w2 = (const float*)d_in[10];
  const float* b2 = (const float*)d_in[11];

  char* base = (char*)d_ws;
  size_t off = 0;
  auto alloc = [&](size_t bytes) -> void* {
    void* p = base + off;
    off += (bytes + 255) & ~(size_t)255;
    return p;
  };
  u16* n1 = (u16*)alloc(1024L * 512 * 2);        // LN1(x[0]) bf16
  u16* qkvc = (u16*)alloc(1024L * 1536 * 2);     // [s][(q|k) h e64] bf16
  u16* wvT = (u16*)alloc(1536L * 512 * 2);       // [h*128+e][d]
  u16* vt = (u16*)alloc(1536L * 1024 * 2);       // v^T [h*128+e][t]
  u16* cat = (u16*)alloc(1024L * 512 * 2);       // concat heads, pad->512
  float* aproj = (float*)alloc(1024L * 512 * 4); // attn @ w_proj + b_proj
  u16* n2 = (u16*)alloc(8192L * 512 * 2);        // LN2 bf16
  u16* hbuf = (u16*)alloc(8192L * 2048 * 2);     // gelu(mlp1) bf16
  u16* BtQKV = (u16*)alloc(1536L * 512 * 2);
  u16* BtP = (u16*)alloc(512L * 512 * 2);
  u16* Bt1 = (u16*)alloc(2048L * 512 * 2);
  u16* Bt2 = (u16*)alloc(512L * 2048 * 2);
  (void)ws_size; (void)in_sizes; (void)n_in; (void)out_size;

  const float scale = 0.15430334996209191f;  // 42^-0.5 folded into q weights

  // all prep + LN1 in one launch (9792 blocks)
  prep_fused<<<9792, 256, 0, stream>>>(wq, wk, wv, w_proj, w1, w2, x, gamma,
                                       beta, BtQKV, wvT, BtP, Bt1, Bt2, cat,
                                       n1, scale);

  // q,k = n1 @ {wq*scale, wk}: [1024,1536], K=512   (nwg=96)
  gemm2<EP_BF16><<<dim3(8, 12, 1), 256, 0, stream>>>(
      n1, 512, 0, BtQKV, 512, 0, qkvc, 1536, 0, 512, nullptr);
  // vt = wvT @ n1^T: [1536,1024], K=512             (nwg=96)
  gemm2<EP_BF16><<<dim3(12, 8, 1), 256, 0, stream>>>(
      wvT, 512, 0, n1, 512, 0, vt, 1024, 0, 512, nullptr);
  // fused attention: scores+softmax+PV+scatter, per (head, 64-row q-tile)
  flash_attn<<<dim3(12, 16), 256, 0, stream>>>(qkvc, vt, cat);
  // attn_proj = concat @ w_proj + b_proj: [1024,512] f32 (nwg=32)
  gemm2<EP_F32B><<<dim3(8, 4, 1), 256, 0, stream>>>(
      cat, 512, 0, BtP, 512, 0, aproj, 512, 0, 512, b_proj);
  // ln2 pre-fills d_out = (x+aproj) + b2 for the atomic MLP2 epilogue
  ln2_kernel<<<8192, 256, 0, stream>>>(x, aproj, gamma, beta, b2, n2,
                                       (float*)d_out);
  // h = gelu(n2 @ w1 + b1): [8192,2048] bf16 (nwg=1024)
  gemm2<EP_GELU><<<dim3(64, 16, 1), 256, 0, stream>>>(
      n2, 512, 0, Bt1, 512, 0, hbuf, 2048, 0, 512, b1);
  // MLP2 split-K=2 (z-slices offset K by 1024): atomicAdd into d_out (nwg=512)
  gemm2<EP_ATOM><<<dim3(64, 4, 2), 256, 0, stream>>>(
      hbuf, 2048, 1024, Bt2, 2048, 1024, d_out, 512, 0, 1024, nullptr);
}

// Round 9
// 158.135 us; speedup vs baseline: 1.1881x; 1.0444x over previous
//
#include <hip/hip_runtime.h>
#include <hip/hip_bf16.h>
#include <stdint.h>

// EncoderBlock: B=8, S=1024, D=512, H=12, HS=42 (padded to 64 for GEMM).
// Only batch 0's attention is used (reference quirk: attn[0] + x).

typedef unsigned short u16;
typedef __attribute__((ext_vector_type(8))) short short8;  // 8 bf16 = 4 VGPRs
typedef __attribute__((ext_vector_type(4))) float f32x4;

__device__ __forceinline__ u16 f2bf(float f) {
  union { float f; unsigned u; } x; x.f = f;
  return (u16)((x.u + 0x7FFFu + ((x.u >> 16) & 1u)) >> 16);  // RNE
}
__device__ __forceinline__ float bf2f(u16 u) {
  union { unsigned u; float f; } x; x.u = ((unsigned)u) << 16;
  return x.f;
}

// async global->LDS, 16B per lane; LDS dest is wave-uniform base + lane*16.
__device__ __forceinline__ void gload_lds16(const u16* g, u16* l) {
  __builtin_amdgcn_global_load_lds(
      (__attribute__((address_space(1))) void*)g,
      (__attribute__((address_space(3))) void*)l, 16, 0, 0);
}

__device__ __forceinline__ float wred_sum(float v) {
#pragma unroll
  for (int off = 32; off > 0; off >>= 1) v += __shfl_xor(v, off, 64);
  return v;
}

// tanh-form GELU: 0.5x(1+tanh(u)) == x / (1 + exp(-2u)), u = c0*x + c1*x^3.
__device__ __forceinline__ float gelu_fast(float t) {
  const float p = __builtin_fmaf(0.0356774081f, t * t, 0.7978845608f);
  return t / (1.0f + __expf(-2.0f * t * p));
}

#define MFMA16x16(a, b, c) __builtin_amdgcn_mfma_f32_16x16x32_bf16(a, b, c, 0, 0, 0)

enum { EP_BF16 = 0, EP_F32B = 2, EP_GELU = 3, EP_ATOM = 7 };

// ---------------------------------------------------------------------------
// GEMM core: C[m][n] = sum_k A[m][k] * Bt[n][k]; 128x128 tile, templated BK
// (32 or 64), 4 waves (2x2), dbuf LDS, one barrier per K-tile (r3/r6-proven).
// ---------------------------------------------------------------------------
template <int EP, int BK>
__device__ __forceinline__ void gemm_core(u16* lds, const u16* __restrict__ Ab,
                                          int lda, const u16* __restrict__ Bb,
                                          int ldb, void* __restrict__ Cv,
                                          int ldc, int K,
                                          const float* __restrict__ bias,
                                          int m0, int n0) {
  constexpr int GPR = BK / 8;    // 16B granules per row (4 or 8)
  constexpr int RPI = 64 / GPR;  // rows per gload instr (16 or 8)
  constexpr int IPM = 32 / RPI;  // instrs per wave chunk per matrix (2 or 4)
  constexpr int TSZ = 128 * BK;  // elements per buffer per matrix
  u16* lA[2] = {lds, lds + TSZ};
  u16* lB[2] = {lds + 2 * TSZ, lds + 3 * TSZ};

  const int tid = threadIdx.x;
  const int w = tid >> 6;
  const int l = tid & 63;
  const int wr = w >> 1;
  const int wc = w & 1;
  const int NT = K / BK;

  f32x4 acc[4][4];
#pragma unroll
  for (int i = 0; i < 4; ++i)
#pragma unroll
    for (int j = 0; j < 4; ++j) acc[i][j] = (f32x4){0.f, 0.f, 0.f, 0.f};

  // staging: wave w covers tile rows [w*32, w*32+32); linear LDS layout.
  const int srow = w * 32 + l / GPR;
  const int sk = (l % GPR) * 8;
  const u16* gA = Ab + (long)(m0 + srow) * lda + sk;
  const u16* gB = Bb + (long)(n0 + srow) * ldb + sk;
  const int dOff = w * 32 * BK;

  // fragment reads: row = l&15, k-granule = l>>4 (+ks*32 per k-subtile)
  const int aoff = (wr * 64 + (l & 15)) * BK + (l >> 4) * 8;
  const int boff = (wc * 64 + (l & 15)) * BK + (l >> 4) * 8;

  auto stage = [&](int b_, int t_) {
#pragma unroll
    for (int i = 0; i < IPM; ++i) {
      gload_lds16(gA + (long)t_ * BK + (long)i * RPI * lda,
                  lA[b_] + dOff + i * RPI * BK);
      gload_lds16(gB + (long)t_ * BK + (long)i * RPI * ldb,
                  lB[b_] + dOff + i * RPI * BK);
    }
  };

  stage(0, 0);
  __syncthreads();

  int buf = 0;
  for (int t = 0; t < NT; ++t) {
    if (t + 1 < NT) stage(buf ^ 1, t + 1);
#pragma unroll
    for (int ks = 0; ks < BK / 32; ++ks) {
      short8 af[4], bfv[4];
#pragma unroll
      for (int mi = 0; mi < 4; ++mi)
        af[mi] = *(const short8*)&lA[buf][aoff + mi * 16 * BK + ks * 32];
#pragma unroll
      for (int ni = 0; ni < 4; ++ni)
        bfv[ni] = *(const short8*)&lB[buf][boff + ni * 16 * BK + ks * 32];
#pragma unroll
      for (int mi = 0; mi < 4; ++mi)
#pragma unroll
        for (int ni = 0; ni < 4; ++ni)
          acc[mi][ni] = MFMA16x16(af[mi], bfv[ni], acc[mi][ni]);
    }
    __syncthreads();
    buf ^= 1;
  }

  // C/D mapping: col = lane&15, row = (lane>>4)*4 + reg  [m89-verified]
  const int rbase = m0 + wr * 64 + (l >> 4) * 4;
  const int cbase = n0 + wc * 64 + (l & 15);
#pragma unroll
  for (int mi = 0; mi < 4; ++mi) {
#pragma unroll
    for (int ni = 0; ni < 4; ++ni) {
#pragma unroll
      for (int j = 0; j < 4; ++j) {
        const int row = rbase + mi * 16 + j;
        const int col = cbase + ni * 16;
        const float v = acc[mi][ni][j];
        if (EP == EP_BF16) {
          ((u16*)Cv)[(long)row * ldc + col] = f2bf(v);
        } else if (EP == EP_F32B) {
          ((float*)Cv)[(long)row * ldc + col] = v + bias[col];
        } else if (EP == EP_GELU) {
          ((u16*)Cv)[(long)row * ldc + col] = f2bf(gelu_fast(v + bias[col]));
        } else {  // EP_ATOM: accumulate into pre-filled output
          atomicAdd(&((float*)Cv)[(long)row * ldc + col], v);
        }
      }
    }
  }
}

// XCD swizzle with bx SLOWEST inside each per-XCD chunk: XCD j owns a
// contiguous bx range across all (by,z) -> per-XCD working set = few A panels
// + all of B, L2-resident (fixes the 66MB A re-stream seen in r8).
template <int EP, int BK>
__launch_bounds__(256, (BK == 32 ? 4 : 2))
__global__ void gemm_k(const u16* __restrict__ A, int lda, long sAz,
                       const u16* __restrict__ Bt, int ldb, long sBz,
                       void* __restrict__ Cv, int ldc, int K,
                       const float* __restrict__ bias) {
  __shared__ u16 lds[4 * 128 * BK];
  const int gx = gridDim.x, gy = gridDim.y, gz = gridDim.z;
  const int lin = blockIdx.x + gx * (blockIdx.y + gy * blockIdx.z);
  const int nwg = gx * gy * gz;
  const int wg = (lin & 7) * (nwg >> 3) + (lin >> 3);
  const int by = wg % gy;
  const int rem = wg / gy;
  const int z = rem % gz;
  const int bx = rem / gz;
  const u16* Ab = A + (long)z * sAz;  // for EP_ATOM: sAz/sBz = k-offset
  const u16* Bb = Bt + (long)z * sBz;
  gemm_core<EP, BK>(lds, Ab, lda, Bb, ldb, Cv, ldc, K, bias, bx * 128,
                    by * 128);
}

// merged q/k + v^T projections: 192 blocks; wg<96 -> qk (8x12 tiles of
// [1024,1536]), wg>=96 -> vt (12x8 tiles of [1536,1024]). One launch instead
// of two serialized 96-block launches.
__launch_bounds__(256, 4)
__global__ void qkvt_kernel(const u16* __restrict__ n1,
                            const u16* __restrict__ BtQKV,
                            u16* __restrict__ qkvc,
                            const u16* __restrict__ wvT,
                            u16* __restrict__ vt) {
  __shared__ u16 lds[4 * 128 * 32];
  const int lin = blockIdx.x;  // 192
  const int wg = (lin & 7) * 24 + (lin >> 3);
  if (wg < 96) {
    gemm_core<EP_BF16, 32>(lds, n1, 512, BtQKV, 512, qkvc, 1536, 512, nullptr,
                           (wg & 7) * 128, (wg >> 3) * 128);
  } else {
    const int v = wg - 96;
    gemm_core<EP_BF16, 32>(lds, wvT, 512, n1, 512, vt, 1024, 512, nullptr,
                           (v % 12) * 128, (v / 12) * 128);
  }
}

// ---------------------------------------------------------------------------
// flash attention (r8-proven): one block per (head, 64-row q-tile).
// ---------------------------------------------------------------------------
__device__ __forceinline__ short8 frag_read(const u16* base, int row, int ks,
                                            int l) {
  const int g = (ks * 4 + (l >> 4)) ^ (l & 7);
  return *(const short8*)&base[row * 64 + g * 8];
}

__launch_bounds__(256, 2)
__global__ void flash_attn(const u16* __restrict__ qkvc,
                           const u16* __restrict__ vt,
                           u16* __restrict__ cat) {
  __shared__ u16 lQ[64 * 64];      // 8KB
  __shared__ u16 lK[2][64 * 64];   // 16KB
  __shared__ u16 lV[2][64 * 64];   // 16KB (rows = e, cols = kv; from vt)
  __shared__ u16 lP[4][16 * 64];   // 8KB, per-wave private
  const int h = blockIdx.x;
  const int q0 = blockIdx.y * 64;
  const int tid = threadIdx.x;
  const int w = tid >> 6;
  const int l = tid & 63;
  const int sg = ((l & 7) ^ (l >> 3)) * 8;  // inverse-swizzled source granule
  const int sr = w * 8 + (l >> 3);          // stage row within 32-row chunk

#define FA_STAGE(t_, b_)                                                    \
  do {                                                                      \
    const int kv_ = (t_) * 64;                                              \
    gload_lds16(qkvc + (long)(kv_ + sr) * 1536 + 768 + h * 64 + sg,         \
                lK[b_] + w * 8 * 64);                                       \
    gload_lds16(qkvc + (long)(kv_ + 32 + sr) * 1536 + 768 + h * 64 + sg,    \
                lK[b_] + (32 + w * 8) * 64);                                \
    gload_lds16(vt + (long)(h * 128 + sr) * 1024 + kv_ + sg,                \
                lV[b_] + w * 8 * 64);                                       \
    gload_lds16(vt + (long)(h * 128 + 32 + sr) * 1024 + kv_ + sg,           \
                lV[b_] + (32 + w * 8) * 64);                                \
  } while (0)

  gload_lds16(qkvc + (long)(q0 + sr) * 1536 + h * 64 + sg, lQ + w * 8 * 64);
  gload_lds16(qkvc + (long)(q0 + 32 + sr) * 1536 + h * 64 + sg,
              lQ + (32 + w * 8) * 64);
  FA_STAGE(0, 0);
  __syncthreads();

  const short8 qf0 = frag_read(lQ, w * 16 + (l & 15), 0, l);
  const short8 qf1 = frag_read(lQ, w * 16 + (l & 15), 1, l);

  f32x4 accO[4];
  float m_run[4], l_run[4];
#pragma unroll
  for (int i = 0; i < 4; ++i) {
    accO[i] = (f32x4){0.f, 0.f, 0.f, 0.f};
    m_run[i] = -3.0e38f;
    l_run[i] = 0.f;
  }

  int buf = 0;
  for (int t = 0; t < 16; ++t) {
    if (t + 1 < 16) FA_STAGE(t + 1, buf ^ 1);
    f32x4 s[4];
#pragma unroll
    for (int ni = 0; ni < 4; ++ni) {
      const short8 kf0 = frag_read(lK[buf], ni * 16 + (l & 15), 0, l);
      const short8 kf1 = frag_read(lK[buf], ni * 16 + (l & 15), 1, l);
      s[ni] = MFMA16x16(qf0, kf0, ((f32x4){0.f, 0.f, 0.f, 0.f}));
      s[ni] = MFMA16x16(qf1, kf1, s[ni]);
    }
#pragma unroll
    for (int j = 0; j < 4; ++j) {
      float mx = fmaxf(fmaxf(s[0][j], s[1][j]), fmaxf(s[2][j], s[3][j]));
      mx = fmaxf(mx, __shfl_xor(mx, 1));
      mx = fmaxf(mx, __shfl_xor(mx, 2));
      mx = fmaxf(mx, __shfl_xor(mx, 4));
      mx = fmaxf(mx, __shfl_xor(mx, 8));
      const float mn = fmaxf(m_run[j], mx);
      const float corr = __expf(m_run[j] - mn);
      m_run[j] = mn;
      float ps = 0.f;
#pragma unroll
      for (int ni = 0; ni < 4; ++ni) {
        const float p = __expf(s[ni][j] - mn);
        s[ni][j] = p;
        ps += p;
      }
      ps += __shfl_xor(ps, 1);
      ps += __shfl_xor(ps, 2);
      ps += __shfl_xor(ps, 4);
      ps += __shfl_xor(ps, 8);
      l_run[j] = l_run[j] * corr + ps;
#pragma unroll
      for (int ne = 0; ne < 4; ++ne) accO[ne][j] *= corr;
    }
#pragma unroll
    for (int ni = 0; ni < 4; ++ni) {
#pragma unroll
      for (int j = 0; j < 4; ++j) {
        const int row = (l >> 4) * 4 + j;
        const int col = ni * 16 + (l & 15);
        const int boff = row * 128 + (((col >> 3) ^ (row & 7)) << 4) +
                         (col & 7) * 2;
        *(u16*)((char*)lP[w] + boff) = f2bf(s[ni][j]);
      }
    }
    asm volatile("s_waitcnt lgkmcnt(0)" ::: "memory");
    __builtin_amdgcn_sched_barrier(0);
    const short8 pf0 = frag_read(lP[w], (l & 15), 0, l);
    const short8 pf1 = frag_read(lP[w], (l & 15), 1, l);
#pragma unroll
    for (int ne = 0; ne < 4; ++ne) {
      const short8 vf0 = frag_read(lV[buf], ne * 16 + (l & 15), 0, l);
      const short8 vf1 = frag_read(lV[buf], ne * 16 + (l & 15), 1, l);
      accO[ne] = MFMA16x16(pf0, vf0, accO[ne]);
      accO[ne] = MFMA16x16(pf1, vf1, accO[ne]);
    }
    __syncthreads();
    buf ^= 1;
  }
#undef FA_STAGE

#pragma unroll
  for (int j = 0; j < 4; ++j) {
    const float inv = 1.0f / l_run[j];
    const int row = q0 + w * 16 + (l >> 4) * 4 + j;
#pragma unroll
    for (int ne = 0; ne < 4; ++ne) {
      const int e = ne * 16 + (l & 15);
      if (e < 42)
        cat[(long)row * 512 + h * 42 + e] = f2bf(accO[ne][j] * inv);
    }
  }
}

// ---------------------------------------------------------------------------
// fused prep: weight re-layouts + zero(cat) + LN1, one launch.
// ---------------------------------------------------------------------------
__device__ __forceinline__ void transpose_body(const float* __restrict__ in,
                                               u16* __restrict__ out, int N,
                                               int Kin, int Kpad, int blk,
                                               int gx, int t, float* smem) {
  const int n0 = (blk % gx) * 64;
  const int k0 = (blk / gx) * 64;
  const int tc = t & 63;
  const int tr = t >> 6;  // 0..3
#pragma unroll
  for (int r = 0; r < 16; ++r) {
    const int kr = tr * 16 + r;
    const int kg = k0 + kr;
    smem[kr * 65 + tc] = (kg < Kin) ? in[(long)kg * N + n0 + tc] : 0.f;
  }
  __syncthreads();
  const int nr0 = t >> 4;       // 0..15
  const int kc = (t & 15) * 4;  // 16 lanes x 8B = 128B contiguous per row
#pragma unroll
  for (int p = 0; p < 4; ++p) {
    const int nr = nr0 + p * 16;
    ushort4 v;
    v.x = f2bf(smem[(kc + 0) * 65 + nr]);
    v.y = f2bf(smem[(kc + 1) * 65 + nr]);
    v.z = f2bf(smem[(kc + 2) * 65 + nr]);
    v.w = f2bf(smem[(kc + 3) * 65 + nr]);
    *(ushort4*)&out[(long)(n0 + nr) * Kpad + k0 + kc] = v;
  }
}

__global__ void prep_fused(const float* __restrict__ wq,
                           const float* __restrict__ wk,
                           const float* __restrict__ wv,
                           const float* __restrict__ w_proj,
                           const float* __restrict__ w1,
                           const float* __restrict__ w2,
                           const float* __restrict__ x,
                           const float* __restrict__ gamma,
                           const float* __restrict__ beta,
                           u16* __restrict__ BtQKV, u16* __restrict__ wvT,
                           u16* __restrict__ BtP, u16* __restrict__ Bt1,
                           u16* __restrict__ Bt2, u16* __restrict__ cat,
                           u16* __restrict__ n1, float scale) {
  __shared__ float smem[64 * 65];
  const int blk = blockIdx.x;
  const int t = threadIdx.x;
  if (blk < 3072) {  // BtQKV [1536][512]: n -> (pq, h, e64); q pre-scaled
    const int i = blk * 256 + t;
    const int n = i >> 9, d = i & 511;
    const int pq = n / 768;
    const int h = (n % 768) >> 6;
    const int e = n & 63;
    float v = 0.f;
    if (e < 42) {
      v = (pq ? wk : wq)[((long)h * 512 + d) * 42 + e];
      if (!pq) v *= scale;
    }
    BtQKV[i] = f2bf(v);
  } else if (blk < 6144) {  // wvT [12*128][512]
    const int i = (blk - 3072) * 256 + t;
    const int r = i >> 9, d = i & 511;
    const int h = r >> 7, e = r & 127;
    wvT[i] = f2bf(e < 42 ? wv[((long)h * 512 + d) * 42 + e] : 0.f);
  } else if (blk < 6208) {  // BtP = w_proj^T (pad 504->512)
    transpose_body(w_proj, BtP, 512, 504, 512, blk - 6144, 8, t, smem);
  } else if (blk < 6464) {  // Bt1 = w1^T
    transpose_body(w1, Bt1, 2048, 512, 512, blk - 6208, 32, t, smem);
  } else if (blk < 6720) {  // Bt2 = w2^T
    transpose_body(w2, Bt2, 512, 2048, 2048, blk - 6464, 8, t, smem);
  } else if (blk < 8768) {  // zero cat
    cat[(blk - 6720) * 256 + t] = 0;
  } else {  // ln1 over x[0]
    const int s = blk - 8768;
    const float* row = x + (long)s * 512;
    const float v0 = row[t];
    const float v1 = row[t + 256];
    float sum = wred_sum(v0 + v1);
    float sq = wred_sum(v0 * v0 + v1 * v1);
    if ((t & 63) == 0) { smem[t >> 6] = sum; smem[8 + (t >> 6)] = sq; }
    __syncthreads();
    sum = smem[0] + smem[1] + smem[2] + smem[3];
    sq = smem[8] + smem[9] + smem[10] + smem[11];
    const float mu = sum * (1.0f / 512.0f);
    const float rstd = rsqrtf(sq * (1.0f / 512.0f) - mu * mu + 1e-5f);
    n1[(long)s * 512 + t] = f2bf((v0 - mu) * rstd * gamma[t] + beta[t]);
    n1[(long)s * 512 + t + 256] =
        f2bf((v1 - mu) * rstd * gamma[t + 256] + beta[t + 256]);
  }
}

// ln2: v = x + aproj (bcast); n2 = LN(v); outp = v + b2 (pre-fill for MLP2's
// atomic epilogue).
__global__ void ln2_kernel(const float* __restrict__ x,
                           const float* __restrict__ aproj,
                           const float* __restrict__ gamma,
                           const float* __restrict__ beta,
                           const float* __restrict__ b2,
                           u16* __restrict__ n2, float* __restrict__ outp) {
  __shared__ float red[16];
  const int r = blockIdx.x;  // b*1024 + s
  const int t = threadIdx.x;
  const int s = r & 1023;
  const float* xr = x + (long)r * 512;
  const float* ar = aproj + (long)s * 512;
  const float v0 = xr[t] + ar[t];
  const float v1 = xr[t + 256] + ar[t + 256];
  outp[(long)r * 512 + t] = v0 + b2[t];
  outp[(long)r * 512 + t + 256] = v1 + b2[t + 256];
  float sum = wred_sum(v0 + v1);
  float sq = wred_sum(v0 * v0 + v1 * v1);
  if ((t & 63) == 0) { red[t >> 6] = sum; red[8 + (t >> 6)] = sq; }
  __syncthreads();
  sum = red[0] + red[1] + red[2] + red[3];
  sq = red[8] + red[9] + red[10] + red[11];
  const float mu = sum * (1.0f / 512.0f);
  const float rstd = rsqrtf(sq * (1.0f / 512.0f) - mu * mu + 1e-5f);
  n2[(long)r * 512 + t] = f2bf((v0 - mu) * rstd * gamma[t] + beta[t]);
  n2[(long)r * 512 + t + 256] =
      f2bf((v1 - mu) * rstd * gamma[t + 256] + beta[t + 256]);
}

// ---------------------------------------------------------------------------
extern "C" void kernel_launch(void* const* d_in, const int* in_sizes, int n_in,
                              void* d_out, int out_size, void* d_ws,
                              size_t ws_size, hipStream_t stream) {
  const float* x = (const float*)d_in[0];
  const float* wk = (const float*)d_in[1];   // wk before wq in dict order
  const float* wq = (const float*)d_in[2];
  const float* wv = (const float*)d_in[3];
  const float* w_proj = (const float*)d_in[4];
  const float* b_proj = (const float*)d_in[5];
  const float* gamma = (const float*)d_in[6];
  const float* beta = (const float*)d_in[7];
  const float* w1 = (const float*)d_in[8];
  const float* b1 = (const float*)d_in[9];
  const float* w2 = (const float*)d_in[10];
  const float* b2 = (const float*)d_in[11];

  char* base = (char*)d_ws;
  size_t off = 0;
  auto alloc = [&](size_t bytes) -> void* {
    void* p = base + off;
    off += (bytes + 255) & ~(size_t)255;
    return p;
  };
  u16* n1 = (u16*)alloc(1024L * 512 * 2);        // LN1(x[0]) bf16
  u16* qkvc = (u16*)alloc(1024L * 1536 * 2);     // [s][(q|k) h e64] bf16
  u16* wvT = (u16*)alloc(1536L * 512 * 2);       // [h*128+e][d]
  u16* vt = (u16*)alloc(1536L * 1024 * 2);       // v^T [h*128+e][t]
  u16* cat = (u16*)alloc(1024L * 512 * 2);       // concat heads, pad->512
  float* aproj = (float*)alloc(1024L * 512 * 4); // attn @ w_proj + b_proj
  u16* n2 = (u16*)alloc(8192L * 512 * 2);        // LN2 bf16
  u16* hbuf = (u16*)alloc(8192L * 2048 * 2);     // gelu(mlp1) bf16
  u16* BtQKV = (u16*)alloc(1536L * 512 * 2);
  u16* BtP = (u16*)alloc(512L * 512 * 2);
  u16* Bt1 = (u16*)alloc(2048L * 512 * 2);
  u16* Bt2 = (u16*)alloc(512L * 2048 * 2);
  (void)ws_size; (void)in_sizes; (void)n_in; (void)out_size;

  const float scale = 0.15430334996209191f;  // 42^-0.5 folded into q weights

  // all prep + LN1 in one launch (9792 blocks)
  prep_fused<<<9792, 256, 0, stream>>>(wq, wk, wv, w_proj, w1, w2, x, gamma,
                                       beta, BtQKV, wvT, BtP, Bt1, Bt2, cat,
                                       n1, scale);
  // merged q,k and v^T projections (192 blocks, one launch)
  qkvt_kernel<<<192, 256, 0, stream>>>(n1, BtQKV, qkvc, wvT, vt);
  // fused attention: scores+softmax+PV+scatter
  flash_attn<<<dim3(12, 16), 256, 0, stream>>>(qkvc, vt, cat);
  // attn_proj = concat @ w_proj + b_proj: [1024,512] f32 (nwg=32)
  gemm_k<EP_F32B, 32><<<dim3(8, 4, 1), 256, 0, stream>>>(
      cat, 512, 0, BtP, 512, 0, aproj, 512, 512, b_proj);
  // ln2 pre-fills d_out = (x+aproj) + b2 for the atomic MLP2 epilogue
  ln2_kernel<<<8192, 256, 0, stream>>>(x, aproj, gamma, beta, b2, n2,
                                       (float*)d_out);
  // h = gelu(n2 @ w1 + b1): [8192,2048] bf16 (nwg=1024, BK=32)
  gemm_k<EP_GELU, 32><<<dim3(64, 16, 1), 256, 0, stream>>>(
      n2, 512, 0, Bt1, 512, 0, hbuf, 2048, 512, b1);
  // MLP2 split-K=2, BK=64 (A/B vs MLP1's BK=32): atomicAdd into d_out
  gemm_k<EP_ATOM, 64><<<dim3(64, 4, 2), 256, 0, stream>>>(
      hbuf, 2048, 1024, Bt2, 2048, 1024, d_out, 512, 1024, nullptr);
}